// Round 11
// baseline (150.377 us; speedup 1.0000x reference)
//
#include <hip/hip_runtime.h>

// Morphological max-plus dilation, 'same' padding, K=5.
// out[b,o,y,x] = max_{c,i,j} f[b,c,y+i-2,x+j-2] + h[o,c,i,j]
// f(8,32,96,96) fp32, h(32,32,5,5) fp32, out(8,32,96,96) fp32.
//
// R11 = R10's register-pinned batch loads, made compilable: pin SCALAR
// unsigneds (asm "+v" on uint4 is unsupported -- "tied indirect register
// inputs"). Theory unchanged: dur ~90us is ~51us real VALU (4-cyc non-FMA
// pk rate) + ~39us exposed load latency because the compiler sinks the h &
// window batches to their use sites (R8 VGPR=32, R9 VGPR=56 prove it).
// Batch 10 uint4 window loads + 13 wide LDS h reads per c, extract to
// scalars, pin each -> one vmcnt + one lgkm wait per c, then 800 cyc of
// pure v_pk math.
//  - packed-fp16 math (absmax 0.031 << 0.1 threshold)
//  - f pre-padded in d_ws as DUPLICATED half2 (v,v) dwords with NEG halo
//  - 1536 blocks x 384 thr, CS=4 c-split, RT=4 (R8 structure)

#define B_ 8
#define C_ 32
#define O_ 32
#define H_ 96
#define W_ 96
#define K_ 5
#define KK_ (K_ * K_)      // 25

#define TX_ 24             // threads along x; 24*4 = 96 = W
#define RT_ 4              // row-threads per group (4 output rows per block)
#define CS_ 4              // in-block c-split groups
#define TY_ (RT_ * CS_)    // 16
#define NT_ (TX_ * TY_)    // 384 threads = 6 waves
#define XR_ 4              // x outputs per thread
#define OP_ 2              // half2 o-pairs per thread
#define OB_ (OP_ * 2)      // 4 o-channels per block
#define CG_ (C_ / CS_)     // 8 c's per group

// padded f: [b][c][PH][PW] dwords; row = y+2 (0..99), col = x+2 (pad to 104)
#define PH_ 100
#define PW_ 104
#define PLSZ_ (PH_ * PW_)
#define FPAD_BYTES ((size_t)B_ * C_ * PLSZ_ * 4)

#define NEGF (-30000.0f)

typedef _Float16 h2 __attribute__((ext_vector_type(2)));

static __device__ __forceinline__ h2 h2b(unsigned u) {
    return __builtin_bit_cast(h2, u);
}
static __device__ __forceinline__ unsigned bh2(h2 v) {
    return __builtin_bit_cast(unsigned, v);
}

// ---------------- pre-pad: f fp32 -> duplicated half2 with NEG halo ----------
__global__ __launch_bounds__(256)
void prepad_kernel(const float* __restrict__ f, unsigned* __restrict__ fpad) {
    const int idx = blockIdx.x * 256 + threadIdx.x;
    const int c = blockIdx.y;
    const int b = blockIdx.z;
    if (idx >= PLSZ_) return;
    const int row = idx / PW_;
    const int col = idx - row * PW_;
    const int y = row - 2;
    const int x = col - 2;
    float v = NEGF;
    if ((unsigned)y < H_ && (unsigned)x < W_)
        v = f[((size_t)(b * C_ + c) * H_ + y) * W_ + x];
    _Float16 hv = (_Float16)v;
    h2 d; d.x = hv; d.y = hv;
    fpad[(size_t)(b * C_ + c) * PLSZ_ + idx] = bh2(d);
}

// ---------------- main kernel ------------------------------------------------
template <bool PADDED>
__global__ __launch_bounds__(NT_)
void dilate_main(const unsigned* __restrict__ fpad,
                 const float* __restrict__ f,
                 const float* __restrict__ h, float* __restrict__ out) {
    const int tx  = threadIdx.x;           // 0..23
    const int ty  = threadIdx.y;           // 0..15
    const int tid = ty * TX_ + tx;         // 0..383
    const int ry  = ty & (RT_ - 1);        // row-thread 0..3
    const int g   = ty >> 2;               // c-split group 0..3

    const int ytile = blockIdx.x;          // 0..23
    const int og    = blockIdx.y;          // 0..7
    const int b     = blockIdx.z;          // 0..7
    const int y0 = ytile * RT_;            // 4 rows per block
    const int o0 = og * OB_;
    const int x0 = XR_ * tx;               // 0..92
    const int yb = y0 + ry;                // this thread's output row

    // h per c stored CONTIGUOUS: hs2[c][ij*2+op], 50 dwords used, 64 stride
    __shared__ unsigned hs2[C_][64];                          // 8192 B
    __shared__ unsigned comb[CS_ - 1][OP_ * XR_][RT_ * TX_];  // 9216 B

    // stage h: dword = h2(h[o0+2op][c][ij], h[o0+2op+1][c][ij])
    for (int idx = tid; idx < C_ * KK_ * OP_; idx += NT_) {
        int c  = idx / (KK_ * OP_);
        int rr = idx - c * (KK_ * OP_);
        int ij = rr / OP_;
        int op = rr - ij * OP_;
        int o  = o0 + 2 * op;
        float a0 = h[((size_t)o * C_ + c) * KK_ + ij];
        float a1 = h[((size_t)(o + 1) * C_ + c) * KK_ + ij];
        h2 p; p.x = (_Float16)a0; p.y = (_Float16)a1;
        hs2[c][ij * OP_ + op] = bh2(p);
    }
    __syncthreads();

    h2 acc[OP_][XR_];
    {
        h2 neg; neg.x = (_Float16)NEGF; neg.y = (_Float16)NEGF;
#pragma unroll
        for (int op = 0; op < OP_; ++op)
#pragma unroll
            for (int xx = 0; xx < XR_; ++xx) acc[op][xx] = neg;
    }

    const int c0 = g * CG_;
    for (int cc = 0; cc < CG_; ++cc) {
        const int c = c0 + cc;

        // ---- batched window loads (10 x uint4 from global) -> scalars -------
        unsigned win[K_][8];
        if (PADDED) {
            const unsigned* p =
                fpad + (size_t)(b * C_ + c) * PLSZ_ + yb * PW_ + x0;
#pragma unroll
            for (int i = 0; i < K_; ++i) {
                const uint4* q = (const uint4*)(p + i * PW_);
                uint4 w0 = q[0];
                uint4 w1 = q[1];
                win[i][0] = w0.x; win[i][1] = w0.y;
                win[i][2] = w0.z; win[i][3] = w0.w;
                win[i][4] = w1.x; win[i][5] = w1.y;
                win[i][6] = w1.z; win[i][7] = w1.w;
            }
        } else {
            const float* fc = f + (size_t)(b * C_ + c) * (H_ * W_);
#pragma unroll
            for (int i = 0; i < K_; ++i) {
#pragma unroll
                for (int q = 0; q < 8; ++q) {
                    int yy = yb + i - 2;
                    int xc = x0 - 2 + q;
                    bool ok = ((unsigned)yy < H_) && ((unsigned)xc < W_);
                    float v = ok ? fc[(size_t)yy * W_ + xc] : NEGF;
                    _Float16 hv = (_Float16)v;
                    h2 d; d.x = hv; d.y = hv;
                    win[i][q] = bh2(d);
                }
            }
        }

        // ---- batched h loads (12 x uint4 + 1 x uint2 from LDS) -> scalars ---
        unsigned hu[2 * KK_];
        {
            const uint4* hsrc = (const uint4*)&hs2[c][0];
#pragma unroll
            for (int k = 0; k < 12; ++k) {
                uint4 v = hsrc[k];
                hu[4 * k]     = v.x;
                hu[4 * k + 1] = v.y;
                hu[4 * k + 2] = v.z;
                hu[4 * k + 3] = v.w;
            }
            uint2 hd = *(const uint2*)&hs2[c][48];
            hu[48] = hd.x;
            hu[49] = hd.y;
        }

        // ---- PIN: force all batch loads to materialize here (scalar "+v") ---
#pragma unroll
        for (int n = 0; n < 2 * KK_; ++n) asm volatile("" : "+v"(hu[n]));
#pragma unroll
        for (int i = 0; i < K_; ++i)
#pragma unroll
            for (int q = 0; q < 8; ++q) asm volatile("" : "+v"(win[i][q]));

        // ---- pure-VALU math (constant indices after unroll) -----------------
#pragma unroll
        for (int i = 0; i < K_; ++i) {
#pragma unroll
            for (int j = 0; j < K_; ++j) {
                h2 h0 = h2b(hu[(i * K_ + j) * OP_]);
                h2 h1 = h2b(hu[(i * K_ + j) * OP_ + 1]);
#pragma unroll
                for (int xx = 0; xx < XR_; ++xx) {
                    h2 fv = h2b(win[i][xx + j]);
                    acc[0][xx] = __builtin_elementwise_max(acc[0][xx], fv + h0);
                    acc[1][xx] = __builtin_elementwise_max(acc[1][xx], fv + h1);
                }
            }
        }
    }

    // ---- combine the four c-groups via LDS (lane-contiguous, conflict-free) -
    const int t96 = ry * TX_ + tx;   // 0..95 within group
    if (g > 0) {
#pragma unroll
        for (int op = 0; op < OP_; ++op)
#pragma unroll
            for (int xx = 0; xx < XR_; ++xx)
                comb[g - 1][op * XR_ + xx][t96] = bh2(acc[op][xx]);
    }
    __syncthreads();
    if (g == 0) {
#pragma unroll
        for (int op = 0; op < OP_; ++op)
#pragma unroll
            for (int xx = 0; xx < XR_; ++xx) {
                const int row = op * XR_ + xx;
                h2 v0 = h2b(comb[0][row][t96]);
                h2 v1 = h2b(comb[1][row][t96]);
                h2 v2 = h2b(comb[2][row][t96]);
                h2 m = __builtin_elementwise_max(v0, v1);
                m = __builtin_elementwise_max(m, v2);
                acc[op][xx] = __builtin_elementwise_max(acc[op][xx], m);
            }

        // epilogue: unpack to fp32, coalesced float4 per o-plane
        const int y = yb;
#pragma unroll
        for (int op = 0; op < OP_; ++op) {
            const int o = o0 + 2 * op;
            float4 lo = make_float4((float)acc[op][0].x, (float)acc[op][1].x,
                                    (float)acc[op][2].x, (float)acc[op][3].x);
            float4 hi = make_float4((float)acc[op][0].y, (float)acc[op][1].y,
                                    (float)acc[op][2].y, (float)acc[op][3].y);
            *(float4*)&out[(((size_t)b * O_ + o)     * H_ + y) * W_ + x0] = lo;
            *(float4*)&out[(((size_t)b * O_ + o + 1) * H_ + y) * W_ + x0] = hi;
        }
    }
}

extern "C" void kernel_launch(void* const* d_in, const int* in_sizes, int n_in,
                              void* d_out, int out_size, void* d_ws, size_t ws_size,
                              hipStream_t stream) {
    const float* f = (const float*)d_in[0];
    const float* h = (const float*)d_in[1];
    float* out = (float*)d_out;

    dim3 mgrid(H_ / RT_, O_ / OB_, B_);   // (24, 8, 8) = 1536 blocks
    dim3 mblock(TX_, TY_);                // 384 threads = 6 waves

    if (ws_size >= FPAD_BYTES) {
        unsigned* fpad = (unsigned*)d_ws;
        dim3 pgrid((PLSZ_ + 255) / 256, C_, B_);
        hipLaunchKernelGGL(prepad_kernel, pgrid, dim3(256), 0, stream, f, fpad);
        hipLaunchKernelGGL((dilate_main<true>), mgrid, mblock, 0, stream,
                           fpad, f, h, out);
    } else {
        hipLaunchKernelGGL((dilate_main<false>), mgrid, mblock, 0, stream,
                           (const unsigned*)nullptr, f, h, out);
    }
}

// Round 12
// 144.516 us; speedup vs baseline: 1.0406x; 1.0406x over previous
//
#include <hip/hip_runtime.h>

// Morphological max-plus dilation, 'same' padding, K=5.
// out[b,o,y,x] = max_{c,i,j} f[b,c,y+i-2,x+j-2] + h[o,c,i,j]
// f(8,32,96,96) fp32, h(32,32,5,5) fp32, out(8,32,96,96) fp32.
//
// R12: (1) inner ops pinned to v_pk_add_f16/v_pk_max_f16 via inline asm
// (exact instr count -> busy-time now directly measures cyc/instr);
// (2) C-PAIR packing: padded f stores (f[2cp],f[2cp+1]) per dword instead
// of duplicated (v,v). Each pk op covers 2 c-candidates; acc keeps per-half
// running max, one lo/hi max at the end. Same 3200 pk/thread, but window
// loads, addressing and L1 bytes HALVE (1280 -> 640 B/thread).
//  - packed-fp16 math (absmax 0.031 << 0.1 threshold)
//  - R8 grid: 1536 blocks x 384 thr, 4 c-split groups (4 c-pairs each)

#define B_ 8
#define C_ 32
#define O_ 32
#define H_ 96
#define W_ 96
#define K_ 5
#define KK_ (K_ * K_)      // 25
#define NCP_ (C_ / 2)      // 16 c-pairs

#define TX_ 24             // threads along x; 24*4 = 96 = W
#define RT_ 4              // row-threads per group (4 output rows per block)
#define CS_ 4              // in-block c-split groups
#define TY_ (RT_ * CS_)    // 16
#define NT_ (TX_ * TY_)    // 384 threads = 6 waves
#define XR_ 4              // x outputs per thread
#define OB_ 4              // o-channels per block (one per acc row)
#define CPG_ (NCP_ / CS_)  // 4 c-pairs per group

// padded f: [b][cp][PH][PW] dwords; row = y+2 (0..99), col = x+2 (pad to 104)
#define PH_ 100
#define PW_ 104
#define PLSZ_ (PH_ * PW_)
#define FPAD_BYTES ((size_t)B_ * NCP_ * PLSZ_ * 4)   // ~5.3 MB

#define NEGF (-30000.0f)

typedef _Float16 h2 __attribute__((ext_vector_type(2)));

static __device__ __forceinline__ h2 h2b(unsigned u) {
    return __builtin_bit_cast(h2, u);
}
static __device__ __forceinline__ unsigned bh2(h2 v) {
    return __builtin_bit_cast(unsigned, v);
}

// acc = pk_max(acc, pk_add(fv, hv)) -- instruction selection pinned.
static __device__ __forceinline__ void pk_addmax(h2& acc, h2 fv, h2 hv) {
    h2 t;
    asm("v_pk_add_f16 %0, %1, %2" : "=v"(t) : "v"(fv), "v"(hv));
    asm("v_pk_max_f16 %0, %1, %2" : "=v"(acc) : "v"(acc), "v"(t));
}

// ---------------- pre-pad: two c-planes packed per dword, NEG halo -----------
__global__ __launch_bounds__(256)
void prepad_kernel(const float* __restrict__ f, unsigned* __restrict__ fpad) {
    const int idx = blockIdx.x * 256 + threadIdx.x;
    const int cp = blockIdx.y;            // 0..15
    const int b  = blockIdx.z;
    if (idx >= PLSZ_) return;
    const int row = idx / PW_;
    const int col = idx - row * PW_;
    const int y = row - 2;
    const int x = col - 2;
    float v0 = NEGF, v1 = NEGF;
    if ((unsigned)y < H_ && (unsigned)x < W_) {
        v0 = f[((size_t)(b * C_ + 2 * cp)     * H_ + y) * W_ + x];
        v1 = f[((size_t)(b * C_ + 2 * cp + 1) * H_ + y) * W_ + x];
    }
    h2 d; d.x = (_Float16)v0; d.y = (_Float16)v1;
    fpad[(size_t)(b * NCP_ + cp) * PLSZ_ + idx] = bh2(d);
}

// ---------------- main kernel ------------------------------------------------
template <bool PADDED>
__global__ __launch_bounds__(NT_)
void dilate_main(const unsigned* __restrict__ fpad,
                 const float* __restrict__ f,
                 const float* __restrict__ h, float* __restrict__ out) {
    const int tx  = threadIdx.x;           // 0..23
    const int ty  = threadIdx.y;           // 0..15
    const int tid = ty * TX_ + tx;         // 0..383
    const int ry  = ty & (RT_ - 1);        // row-thread 0..3
    const int g   = ty >> 2;               // c-split group 0..3

    const int ytile = blockIdx.x;          // 0..23
    const int og    = blockIdx.y;          // 0..7
    const int b     = blockIdx.z;          // 0..7
    const int y0 = ytile * RT_;            // 4 rows per block
    const int o0 = og * OB_;
    const int x0 = XR_ * tx;               // 0..92
    const int yb = y0 + ry;                // this thread's output row

    // hs2[cp][ij*4+o] = h2(h[o0+o][2cp][ij], h[o0+o][2cp+1][ij]); stride 104
    __shared__ unsigned hs2[NCP_][104];                      // 6656 B
    __shared__ unsigned comb[CS_ - 1][OB_ * XR_][RT_ * TX_]; // 3*16*96*4 = 18432 B

    for (int idx = tid; idx < NCP_ * KK_ * OB_; idx += NT_) {
        int cp = idx / (KK_ * OB_);
        int rr = idx - cp * (KK_ * OB_);
        int ij = rr / OB_;
        int o  = rr - ij * OB_;
        float a0 = h[((size_t)(o0 + o) * C_ + 2 * cp)     * KK_ + ij];
        float a1 = h[((size_t)(o0 + o) * C_ + 2 * cp + 1) * KK_ + ij];
        h2 p; p.x = (_Float16)a0; p.y = (_Float16)a1;
        hs2[cp][ij * OB_ + o] = bh2(p);
    }
    __syncthreads();

    h2 acc[OB_][XR_];   // per-half running max over its c-subset
    {
        h2 neg; neg.x = (_Float16)NEGF; neg.y = (_Float16)NEGF;
#pragma unroll
        for (int o = 0; o < OB_; ++o)
#pragma unroll
            for (int xx = 0; xx < XR_; ++xx) acc[o][xx] = neg;
    }

    const int cp0 = g * CPG_;
    for (int cpi = 0; cpi < CPG_; ++cpi) {
        const int cp = cp0 + cpi;

        // ---- window: 5 rows x 8 dwords (each dword = 2 c's of one pixel) ----
        h2 win[K_][8];
        if (PADDED) {
            const unsigned* p =
                fpad + (size_t)(b * NCP_ + cp) * PLSZ_ + yb * PW_ + x0;
#pragma unroll
            for (int i = 0; i < K_; ++i) {
                const uint4* q = (const uint4*)(p + i * PW_);
                uint4 w0 = q[0];
                uint4 w1 = q[1];
                win[i][0] = h2b(w0.x); win[i][1] = h2b(w0.y);
                win[i][2] = h2b(w0.z); win[i][3] = h2b(w0.w);
                win[i][4] = h2b(w1.x); win[i][5] = h2b(w1.y);
                win[i][6] = h2b(w1.z); win[i][7] = h2b(w1.w);
            }
        } else {
            const float* fc0 = f + (size_t)(b * C_ + 2 * cp) * (H_ * W_);
            const float* fc1 = f + (size_t)(b * C_ + 2 * cp + 1) * (H_ * W_);
#pragma unroll
            for (int i = 0; i < K_; ++i) {
#pragma unroll
                for (int q = 0; q < 8; ++q) {
                    int yy = yb + i - 2;
                    int xc = x0 - 2 + q;
                    bool ok = ((unsigned)yy < H_) && ((unsigned)xc < W_);
                    float v0 = ok ? fc0[(size_t)yy * W_ + xc] : NEGF;
                    float v1 = ok ? fc1[(size_t)yy * W_ + xc] : NEGF;
                    h2 d; d.x = (_Float16)v0; d.y = (_Float16)v1;
                    win[i][q] = d;
                }
            }
        }

        // ---- math: per (ij): one uint4 h read, 16 pk_add + 16 pk_max --------
#pragma unroll
        for (int i = 0; i < K_; ++i) {
#pragma unroll
            for (int j = 0; j < K_; ++j) {
                uint4 hq = *(const uint4*)&hs2[cp][(i * K_ + j) * OB_];
                h2 h0 = h2b(hq.x), h1 = h2b(hq.y);
                h2 h02 = h2b(hq.z), h3 = h2b(hq.w);
#pragma unroll
                for (int xx = 0; xx < XR_; ++xx) {
                    h2 fv = win[i][xx + j];
                    pk_addmax(acc[0][xx], fv, h0);
                    pk_addmax(acc[1][xx], fv, h1);
                    pk_addmax(acc[2][xx], fv, h02);
                    pk_addmax(acc[3][xx], fv, h3);
                }
            }
        }
    }

    // ---- combine the four c-groups via LDS (lane-contiguous) ----------------
    const int t96 = ry * TX_ + tx;   // 0..95 within group
    if (g > 0) {
#pragma unroll
        for (int o = 0; o < OB_; ++o)
#pragma unroll
            for (int xx = 0; xx < XR_; ++xx)
                comb[g - 1][o * XR_ + xx][t96] = bh2(acc[o][xx]);
    }
    __syncthreads();
    if (g == 0) {
#pragma unroll
        for (int o = 0; o < OB_; ++o)
#pragma unroll
            for (int xx = 0; xx < XR_; ++xx) {
                const int row = o * XR_ + xx;
                h2 v0 = h2b(comb[0][row][t96]);
                h2 v1 = h2b(comb[1][row][t96]);
                h2 v2 = h2b(comb[2][row][t96]);
                h2 m = __builtin_elementwise_max(v0, v1);
                m = __builtin_elementwise_max(m, v2);
                acc[o][xx] = __builtin_elementwise_max(acc[o][xx], m);
            }

        // epilogue: reduce c-pair halves, unpack to fp32, float4 per o-plane
        const int y = yb;
#pragma unroll
        for (int o = 0; o < OB_; ++o) {
            float r[XR_];
#pragma unroll
            for (int xx = 0; xx < XR_; ++xx)
                r[xx] = fmaxf((float)acc[o][xx].x, (float)acc[o][xx].y);
            float4 v = make_float4(r[0], r[1], r[2], r[3]);
            *(float4*)&out[(((size_t)b * O_ + (o0 + o)) * H_ + y) * W_ + x0] = v;
        }
    }
}

extern "C" void kernel_launch(void* const* d_in, const int* in_sizes, int n_in,
                              void* d_out, int out_size, void* d_ws, size_t ws_size,
                              hipStream_t stream) {
    const float* f = (const float*)d_in[0];
    const float* h = (const float*)d_in[1];
    float* out = (float*)d_out;

    dim3 mgrid(H_ / RT_, O_ / OB_, B_);   // (24, 8, 8) = 1536 blocks
    dim3 mblock(TX_, TY_);                // 384 threads = 6 waves

    if (ws_size >= FPAD_BYTES) {
        unsigned* fpad = (unsigned*)d_ws;
        dim3 pgrid((PLSZ_ + 255) / 256, NCP_, B_);
        hipLaunchKernelGGL(prepad_kernel, pgrid, dim3(256), 0, stream, f, fpad);
        hipLaunchKernelGGL((dilate_main<true>), mgrid, mblock, 0, stream,
                           fpad, f, h, out);
    } else {
        hipLaunchKernelGGL((dilate_main<false>), mgrid, mblock, 0, stream,
                           (const unsigned*)nullptr, f, h, out);
    }
}